// Round 4
// baseline (255.692 us; speedup 1.0000x reference)
//
#include <hip/hip_runtime.h>
#include <math.h>

namespace {
constexpr int NIN   = 32;
constexpr int H_    = 14;
constexpr int CIN   = 8;
constexpr int C_    = 32;
constexpr int COUT  = 16;
constexpr int R_    = 288;
constexpr int W_    = 12;
constexpr int NITER = 3;
constexpr int CH    = 32;              // r per compute chunk
constexpr int NCH   = 9;               // 288/32
constexpr int NPH   = 18;              // half-chunk phases
constexpr size_t XSUB = (size_t)NIN * H_ * H_ * CIN;   // x stride per batch elem
}

typedef unsigned int u32;
typedef const __attribute__((address_space(1))) u32* as1_u32p;
typedef __attribute__((address_space(3))) u32* as3_u32p;

__device__ __forceinline__ void async_copy16(const void* g, void* l) {
    __builtin_amdgcn_global_load_lds((as1_u32p)g, (as3_u32p)l, 16, 0, 0);
}
__device__ __forceinline__ float dot4(const float4 a, const float4 b) {
    return fmaf(a.x, b.x, fmaf(a.y, b.y, fmaf(a.z, b.z, a.w * b.w)));
}
// VALU-pipe cross-lane ops (DPP).
__device__ __forceinline__ float dpp_add_xor1(float v) {
    int t = __builtin_amdgcn_update_dpp(0, __float_as_int(v), 0xB1, 0xF, 0xF, true);
    return v + __int_as_float(t);
}
__device__ __forceinline__ float dpp_add_xor2(float v) {
    int t = __builtin_amdgcn_update_dpp(0, __float_as_int(v), 0x4E, 0xF, 0xF, true);
    return v + __int_as_float(t);
}
__device__ __forceinline__ float dpp_add_shr4(float v) {
    int t = __builtin_amdgcn_update_dpp(0, __float_as_int(v), 0x114, 0xF, 0xF, true);
    return v + __int_as_float(t);
}
__device__ __forceinline__ float dpp_add_shr8(float v) {
    int t = __builtin_amdgcn_update_dpp(0, __float_as_int(v), 0x118, 0xF, 0xF, true);
    return v + __int_as_float(t);
}
template <int CTRL>
__device__ __forceinline__ float dpp_bc(float v) {   // quad broadcast (mov)
    return __int_as_float(
        __builtin_amdgcn_update_dpp(0, __float_as_int(v), CTRL, 0xF, 0xF, true));
}

// R16: latency-bound diagnosis (R15: +VALU work absorbed at flat wall).
// Priors loop = deep counted-vmcnt pipeline at UNCHANGED 4-block residency:
//   * W staged in half-chunks (8 KB, R13 slot map), 5 buffers = 40 KB
//     exactly; stage distance 4 (~1000 cy cover vs ~1000 cy W-delivery
//     latency). R14 proved counted-vmcnt cuts per-block latency ~25% but
//     lost residency to 48 KB LDS; this keeps both.
//   * raw s_barrier + exact counted s_waitcnt vmcnt(N) lgkmcnt(0); no
//     vmcnt(0) drain inside the loop. NWAIT derived from the issue log
//     (order pinned by sched_barrier(0) fences): xlds then stage(h+4).
//   * xld(8) hoisted to phase 12 so its consumer wait (phase 16) doesn't
//     drain stages 16/17.
//   * sRed/redE aliased into wbuf (routing phase starts after priors;
//     buffer 0's last read is phase 15, certified by barriers).
// Race safety: each wave waits its own stage(h) via vmcnt before barrier;
// lgkmcnt(0) before barrier certifies its ds_reads physically done, so
// stage(h+4) (writes buffer read in phase h-1) issued after barrier h
// cannot race any wave's reads.
// Lessons: 256-thr blocks (R6/R10); no forced waves/EU (R4); zero-VGPR
// global_load_lds staging (R7); priors fp32 (R2); DPP cross-lane (R9/R11);
// VGPR 128-bucket caps occupancy at 16 waves/CU, LDS<=40K free (R13/R14);
// all-wave redundant squash epilogue (R15).
__global__ __launch_bounds__(256)
void caps_routeC(const float* __restrict__ x,
                 const float* __restrict__ rw,
                 float* __restrict__ out)
{
    const int tid = threadIdx.x;
    const int p  = blockIdx.x / W_;
    const int q  = blockIdx.x % W_;
    const int b0 = blockIdx.y * 4;
    const int c  = blockIdx.z;

    // 5 x 8 KB W half-chunk buffers; sRed/redE alias the low bytes
    // (dead during routing/squash).
    __shared__ __align__(16) char smem[40960];
    float (*sRedP)[4][2][16] = reinterpret_cast<float (*)[4][2][16]>(smem);      // [2][4][2][16] @0
    float (*redEP)[4][2]     = reinterpret_cast<float (*)[4][2]>(smem + 1024);   // [2][4][2] @1024

    const int og   = tid & 3;
    const int rl   = tid >> 2;     // 0..63
    const int cr   = rl & 31;      // chunk-local r
    const int sh   = rl >> 5;      // wave-uniform sub-pair select
    const int lane = tid & 63;
    const int wv   = tid >> 6;
    const int sA   = sh * 2;       // first sub of this thread's pair

    // per-lane x base: lane og covers (sub sA + (og>>1), float4-half og&1)
    const float* xq = x + (size_t)(b0 + sA + (og >> 1)) * XSUB + (og & 1) * 4;
    const float4* rwcF4 = (const float4*)(rw + (size_t)c * R_ * CIN * COUT);

    float4 xvb[2];                 // x prefetch slots (static idx under unroll)
    auto xld = [&](int k, int slot) {
        const int r  = k * CH + cr;
        const int n  = r / 9, rem = r - n * 9;
        const int kh = rem / 3, kw = rem - kh * 3;
        xvb[slot] = *(const float4*)(xq + ((n * H_ + (p + kh)) * H_ + (q + kw)) * CIN);
    };

    // Stage half-chunk phase h (chunk h>>1, Cin-half h&1) into buffer h%5.
    // Slot map per R13: s = t*256+tid -> [ii=s>>7][wcr=(s>>2)&31][wog=s&3];
    // global f4 = wcr*32 + (half*4+ii)*4 + wog. 2 insts/thread.
    auto stage = [&](int h) {
        const int k = h >> 1, half = h & 1, buf = h % 5;
        const float4* gchunk = rwcF4 + (size_t)k * (CH * 32);
        #pragma unroll
        for (int t = 0; t < 2; ++t) {
            const int s   = t * 256 + tid;
            const int ii  = s >> 7;
            const int wcr = (s >> 2) & 31;
            async_copy16(gchunk + (wcr * 32 + (half * 4 + ii) * 4 + (s & 3)),
                         smem + buf * 8192 + (t * 256 + (tid & 192)) * 16);
        }
    };

    // Exact outstanding-op counts newer than stage(h) at each phase top,
    // from the pinned issue log (prologue: xld0, st0..st3; even phase j:
    // xld(j/2+1) [j<14], +xld8 at j=12; then stage(j+4)).
    constexpr int NWAIT[NPH] = {6,7,7,8, 7,8,7,8, 7,8,7,8, 7,9,8,6, 2,0};
    auto vwait = [](int n) {
        switch (n) {   // folds to one literal per unrolled phase
          case 2: asm volatile("s_waitcnt vmcnt(2) lgkmcnt(0)" ::: "memory"); break;
          case 6: asm volatile("s_waitcnt vmcnt(6) lgkmcnt(0)" ::: "memory"); break;
          case 7: asm volatile("s_waitcnt vmcnt(7) lgkmcnt(0)" ::: "memory"); break;
          case 8: asm volatile("s_waitcnt vmcnt(8) lgkmcnt(0)" ::: "memory"); break;
          case 9: asm volatile("s_waitcnt vmcnt(9) lgkmcnt(0)" ::: "memory"); break;
          default: asm volatile("s_waitcnt vmcnt(0) lgkmcnt(0)" ::: "memory"); break;
        }
    };

    float4 acc[NCH][2];
    float  fA[8], fB[8];
    float4 a0, a1;

    xld(0, 0);
    stage(0); stage(1); stage(2); stage(3);
    #pragma unroll
    for (int h = 0; h < NPH; ++h) {
        const int k = h >> 1, half = h & 1;
        vwait(NWAIT[h]);                     // own stage(h) landed; rest in flight
        __builtin_amdgcn_s_barrier();
        __builtin_amdgcn_sched_barrier(0);
        if (half == 0) {
            // og-quad exchange: fA = sub sA floats 0..7, fB = sub sA+1 (VALU)
            const float4 cur = xvb[k & 1];
            fA[0] = dpp_bc<0x00>(cur.x); fA[1] = dpp_bc<0x00>(cur.y);
            fA[2] = dpp_bc<0x00>(cur.z); fA[3] = dpp_bc<0x00>(cur.w);
            fA[4] = dpp_bc<0x55>(cur.x); fA[5] = dpp_bc<0x55>(cur.y);
            fA[6] = dpp_bc<0x55>(cur.z); fA[7] = dpp_bc<0x55>(cur.w);
            fB[0] = dpp_bc<0xAA>(cur.x); fB[1] = dpp_bc<0xAA>(cur.y);
            fB[2] = dpp_bc<0xAA>(cur.z); fB[3] = dpp_bc<0xAA>(cur.w);
            fB[4] = dpp_bc<0xFF>(cur.x); fB[5] = dpp_bc<0xFF>(cur.y);
            fB[6] = dpp_bc<0xFF>(cur.z); fB[7] = dpp_bc<0xFF>(cur.w);
            if (k + 1 < 8) xld(k + 1, (k + 1) & 1);   // xld1..7 at phases 0..12
            if (k == 6)    xld(8, 0);                 // xld8 hoisted to phase 12
            a0 = make_float4(0.f, 0.f, 0.f, 0.f);
            a1 = make_float4(0.f, 0.f, 0.f, 0.f);
        }
        __builtin_amdgcn_sched_barrier(0);   // pin: xlds before stage in issue order
        if (h + 4 < NPH) stage(h + 4);
        __builtin_amdgcn_sched_barrier(0);   // pin: stage before compute
        const float4* wb = (const float4*)(smem + (h % 5) * 8192);
        #pragma unroll
        for (int ii = 0; ii < 4; ++ii) {
            const float fa = fA[half * 4 + ii];
            const float fb = fB[half * 4 + ii];
            const float4 wv4 = wb[ii * 128 + cr * 4 + og];   // conflict-free b128
            a0.x = fmaf(fa, wv4.x, a0.x);  a1.x = fmaf(fb, wv4.x, a1.x);
            a0.y = fmaf(fa, wv4.y, a0.y);  a1.y = fmaf(fb, wv4.y, a1.y);
            a0.z = fmaf(fa, wv4.z, a0.z);  a1.z = fmaf(fb, wv4.z, a1.z);
            a0.w = fmaf(fa, wv4.w, a0.w);  a1.w = fmaf(fb, wv4.w, a1.w);
        }
        if (half == 1) { acc[k][0] = a0;  acc[k][1] = a1; }
    }

    float lgA[NCH], lgB[NCH];
    #pragma unroll
    for (int j = 0; j < NCH; ++j) { lgA[j] = 0.f; lgB[j] = 0.f; }

    float4 v0, v1;   // squash output for subs sA, sA+1, couts og*4..og*4+3

    for (int it = 0; it < NITER; ++it) {
        const int par = it & 1;
        float4 s0 = make_float4(0.f, 0.f, 0.f, 0.f);
        float4 s1 = make_float4(0.f, 0.f, 0.f, 0.f);
        float se0 = 0.f, se1 = 0.f;

        if (it == 0) {
            #pragma unroll
            for (int j = 0; j < NCH; ++j) {
                s0.x += acc[j][0].x;  s1.x += acc[j][1].x;
                s0.y += acc[j][0].y;  s1.y += acc[j][1].y;
                s0.z += acc[j][0].z;  s1.z += acc[j][1].z;
                s0.w += acc[j][0].w;  s1.w += acc[j][1].w;
            }
        } else {
            #pragma unroll
            for (int j = 0; j < NCH; ++j) {
                float d0 = dot4(acc[j][0], v0);
                float d1 = dot4(acc[j][1], v1);
                d0 = dpp_add_xor1(d0);  d1 = dpp_add_xor1(d1);   // VALU
                d0 = dpp_add_xor2(d0);  d1 = dpp_add_xor2(d1);
                lgA[j] += d0;                 lgB[j] += d1;
                const float e0 = __expf(lgA[j]);
                const float e1 = __expf(lgB[j]);
                se0 += e0;                    se1 += e1;
                s0.x = fmaf(e0, acc[j][0].x, s0.x);  s1.x = fmaf(e1, acc[j][1].x, s1.x);
                s0.y = fmaf(e0, acc[j][0].y, s0.y);  s1.y = fmaf(e1, acc[j][1].y, s1.y);
                s0.z = fmaf(e0, acc[j][0].z, s0.z);  s1.z = fmaf(e1, acc[j][1].z, s1.z);
                s0.w = fmaf(e0, acc[j][0].w, s0.w);  s1.w = fmaf(e1, acc[j][1].w, s1.w);
            }
            // se: og-redundant; lane bits 2-3 on DPP, 4-5 on swizzle
            se0 = dpp_add_shr4(se0);  se1 = dpp_add_shr4(se1);
            se0 = dpp_add_shr8(se0);  se1 = dpp_add_shr8(se1);
            se0 += __shfl_xor(se0, 16, 64);  se1 += __shfl_xor(se1, 16, 64);
            se0 += __shfl_xor(se0, 32, 64);  se1 += __shfl_xor(se1, 32, 64);
            if (lane == 15) { redEP[par][wv][0] = se0; redEP[par][wv][1] = se1; }
        }

        // s-reduce over the wave's 16 cr-slots: bits 2-3 via DPP row_shr
        // (og-preserving; totals in lanes 12..15), bits 4-5 via swizzle.
        s0.x = dpp_add_shr4(s0.x);  s1.x = dpp_add_shr4(s1.x);
        s0.y = dpp_add_shr4(s0.y);  s1.y = dpp_add_shr4(s1.y);
        s0.z = dpp_add_shr4(s0.z);  s1.z = dpp_add_shr4(s1.z);
        s0.w = dpp_add_shr4(s0.w);  s1.w = dpp_add_shr4(s1.w);
        s0.x = dpp_add_shr8(s0.x);  s1.x = dpp_add_shr8(s1.x);
        s0.y = dpp_add_shr8(s0.y);  s1.y = dpp_add_shr8(s1.y);
        s0.z = dpp_add_shr8(s0.z);  s1.z = dpp_add_shr8(s1.z);
        s0.w = dpp_add_shr8(s0.w);  s1.w = dpp_add_shr8(s1.w);
        #pragma unroll
        for (int off = 16; off <= 32; off <<= 1) {
            s0.x += __shfl_xor(s0.x, off, 64);  s1.x += __shfl_xor(s1.x, off, 64);
            s0.y += __shfl_xor(s0.y, off, 64);  s1.y += __shfl_xor(s1.y, off, 64);
            s0.z += __shfl_xor(s0.z, off, 64);  s1.z += __shfl_xor(s1.z, off, 64);
            s0.w += __shfl_xor(s0.w, off, 64);  s1.w += __shfl_xor(s1.w, off, 64);
        }
        if (lane >= 12 && lane < 16) {   // lanes 12..15, og = lane&3
            *(float4*)&sRedP[par][wv][0][(lane & 3) * 4] = s0;
            *(float4*)&sRedP[par][wv][1][(lane & 3) * 4] = s1;
        }
        __syncthreads();

        // ---- all-wave redundant squash (R15): every thread computes its
        // own og-quad of v for subs sA, sA+1.
        const float4 pa0 = *(const float4*)&sRedP[par][sh * 2    ][0][og * 4];
        const float4 pb0 = *(const float4*)&sRedP[par][sh * 2 + 1][0][og * 4];
        const float4 pa1 = *(const float4*)&sRedP[par][sh * 2    ][1][og * 4];
        const float4 pb1 = *(const float4*)&sRedP[par][sh * 2 + 1][1][og * 4];
        float inv0, inv1;
        if (it == 0) {
            inv0 = inv1 = 1.0f / (float)R_;
        } else {
            inv0 = 1.0f / (redEP[par][sh * 2][0] + redEP[par][sh * 2 + 1][0]);
            inv1 = 1.0f / (redEP[par][sh * 2][1] + redEP[par][sh * 2 + 1][1]);
        }
        float4 sc0, sc1;
        sc0.x = (pa0.x + pb0.x) * inv0;  sc1.x = (pa1.x + pb1.x) * inv1;
        sc0.y = (pa0.y + pb0.y) * inv0;  sc1.y = (pa1.y + pb1.y) * inv1;
        sc0.z = (pa0.z + pb0.z) * inv0;  sc1.z = (pa1.z + pb1.z) * inv1;
        sc0.w = (pa0.w + pb0.w) * inv0;  sc1.w = (pa1.w + pb1.w) * inv1;
        float sn0 = dot4(sc0, sc0);
        float sn1 = dot4(sc1, sc1);
        sn0 = dpp_add_xor1(sn0);  sn1 = dpp_add_xor1(sn1);   // sum over og quad
        sn0 = dpp_add_xor2(sn0);  sn1 = dpp_add_xor2(sn1);
        const float f0 = sqrtf(sn0) / (1.0f + sn0);
        const float f1 = sqrtf(sn1) / (1.0f + sn1);
        v0.x = sc0.x * f0;  v1.x = sc1.x * f1;
        v0.y = sc0.y * f0;  v1.y = sc1.y * f1;
        v0.z = sc0.z * f0;  v1.z = sc1.z * f1;
        v0.w = sc0.w * f0;  v1.w = sc1.w * f1;
        // Next iter writes sRed/redE[!par]; the par-buffer overwrite (it+2)
        // sits behind it+1's barrier.
    }

    if (cr == 0) {   // 8 writer threads: (sh 0..1) x (og 0..3), 2 subs each
        *(float4*)&out[((((size_t)(b0 + sA)     * C_ + c) * W_ + p) * W_ + q) * COUT + og * 4] = v0;
        *(float4*)&out[((((size_t)(b0 + sA + 1) * C_ + c) * W_ + p) * W_ + q) * COUT + og * 4] = v1;
    }
}

extern "C" void kernel_launch(void* const* d_in, const int* in_sizes, int n_in,
                              void* d_out, int out_size, void* d_ws, size_t ws_size,
                              hipStream_t stream) {
    const float* x  = (const float*)d_in[0];
    const float* rw = (const float*)d_in[1];
    float* out = (float*)d_out;
    dim3 grid(W_ * W_, 2, C_);
    caps_routeC<<<grid, 256, 0, stream>>>(x, rw, out);
}

// Round 5
// 196.124 us; speedup vs baseline: 1.3037x; 1.3037x over previous
//
#include <hip/hip_runtime.h>
#include <math.h>

namespace {
constexpr int NIN   = 32;
constexpr int H_    = 14;
constexpr int CIN   = 8;
constexpr int C_    = 32;
constexpr int COUT  = 16;
constexpr int R_    = 288;
constexpr int W_    = 12;
constexpr int NITER = 3;
constexpr int CH    = 32;              // r per chunk
constexpr int NCH   = 9;               // 288/32
constexpr size_t XSUB = (size_t)NIN * H_ * H_ * CIN;   // x stride per batch elem
}

typedef unsigned int u32;
typedef const __attribute__((address_space(1))) u32* as1_u32p;
typedef __attribute__((address_space(3))) u32* as3_u32p;

__device__ __forceinline__ void async_copy16(const void* g, void* l) {
    __builtin_amdgcn_global_load_lds((as1_u32p)g, (as3_u32p)l, 16, 0, 0);
}
__device__ __forceinline__ float dot4(const float4 a, const float4 b) {
    return fmaf(a.x, b.x, fmaf(a.y, b.y, fmaf(a.z, b.z, a.w * b.w)));
}
// VALU-pipe cross-lane ops (DPP) — keep traffic off the DS pipe.
__device__ __forceinline__ float dpp_add_xor1(float v) {
    int t = __builtin_amdgcn_update_dpp(0, __float_as_int(v), 0xB1, 0xF, 0xF, true);
    return v + __int_as_float(t);
}
__device__ __forceinline__ float dpp_add_xor2(float v) {
    int t = __builtin_amdgcn_update_dpp(0, __float_as_int(v), 0x4E, 0xF, 0xF, true);
    return v + __int_as_float(t);
}
__device__ __forceinline__ float dpp_add_shr4(float v) {
    int t = __builtin_amdgcn_update_dpp(0, __float_as_int(v), 0x114, 0xF, 0xF, true);
    return v + __int_as_float(t);
}
__device__ __forceinline__ float dpp_add_shr8(float v) {
    int t = __builtin_amdgcn_update_dpp(0, __float_as_int(v), 0x118, 0xF, 0xF, true);
    return v + __int_as_float(t);
}
template <int CTRL>
__device__ __forceinline__ float dpp_bc(float v) {   // quad broadcast (mov)
    return __int_as_float(
        __builtin_amdgcn_update_dpp(0, __float_as_int(v), CTRL, 0xF, 0xF, true));
}

// R17 = R15 structure (best: 161 us, VALUBusy 63%) + XCD-aware grid swizzle.
// Diagnosis: latency-bound; per-XCD working set today = ALL W (4.7 MB) +
// ALL x (6.4 MB) >> 4 MB L2 -> W/x delivery is L3-class (~500-700 cy),
// and the 9-chunk stage chain (cover ~1 chunk) eats ~15k cy/block.
// Swizzle: 1-D grid 9216; hw%8 = XCD (round-robin dispatch, m09/T1);
// group = y*32 + c; XCD k owns groups 8k..8k+7 -> fixed batch-half
// (x 3.2 MB) + 8 c's (W 1.18 MB) = 4.4 MB ~ L2-resident per XCD.
// 9216 % 8 == 0 -> bijective. Compute structure byte-identical to R15.
// Lessons: 256-thr blocks (R6/R10); no forced waves/EU (R4); zero-VGPR
// global_load_lds + plain __syncthreads (R7; counted-vmcnt 0-for-3:
// R14/R16); priors fp32 (R2); DPP cross-lane (R9/R11); residency pinned
// at 0.62 x min(LDS-cap, 16 waves) — VGPR>=72 closes that book (R13-R16);
// all-wave redundant squash (R15).
__global__ __launch_bounds__(256)
void caps_routeC(const float* __restrict__ x,
                 const float* __restrict__ rw,
                 float* __restrict__ out)
{
    const int tid = threadIdx.x;
    // XCD-aware decode: xcd = hw%8; local covers 8 groups x 144 pq tiles.
    const int hw    = blockIdx.x;
    const int xcd   = hw & 7;
    const int local = hw >> 3;          // 0..1151
    const int pq    = local % 144;
    const int gl    = local / 144;      // 0..7
    const int grp   = xcd * 8 + gl;     // = y*32 + c
    const int yb    = grp >> 5;         // batch-quad index 0..1
    const int c     = grp & 31;
    const int p  = pq / W_;
    const int q  = pq % W_;
    const int b0 = yb * 4;

    __shared__ float4 wbuf[2][1024];     // [buf][i(8)][cr(32)][og(4)] 16 KB each
    __shared__ float  sRed[2][4][2][16]; // [parity][wave][local sub][o]
    __shared__ float  redE[2][4][2];     // [parity][wave][local sub]

    const int og   = tid & 3;
    const int rl   = tid >> 2;     // 0..63
    const int cr   = rl & 31;      // chunk-local r
    const int sh   = rl >> 5;      // wave-uniform: waves 0,1 -> subs 0,1; 2,3 -> 2,3
    const int lane = tid & 63;
    const int wv   = tid >> 6;
    const int sA   = sh * 2;       // first sub of this thread's pair

    // per-lane x base: lane og covers (sub sA + (og>>1), float4-half og&1)
    const float* xq = x + (size_t)(b0 + sA + (og >> 1)) * XSUB + (og & 1) * 4;
    const float4* rwcF4 = (const float4*)(rw + (size_t)c * R_ * CIN * COUT);

    float4 xvb[2];                 // distance-2 x prefetch slots
    auto xld = [&](int k, int slot) {
        const int r  = k * CH + cr;
        const int n  = r / 9, rem = r - n * 9;
        const int kh = rem / 3, kw = rem - kh * 3;
        xvb[slot] = *(const float4*)(xq + ((n * H_ + (p + kh)) * H_ + (q + kw)) * CIN);
    };

    auto stage = [&](int k, int buf) {
        // slot s = t*256+tid -> [ii=s>>7][wcr=(s>>2)&31][wog=s&3];
        // global f4 = wcr*32 + ii*4 + wog (chunk base k*1024 f4)
        const float4* gchunk = rwcF4 + (size_t)k * (CH * 32);
        #pragma unroll
        for (int t = 0; t < 4; ++t) {
            const int s   = t * 256 + tid;
            const int ii  = s >> 7;
            const int wcr = (s >> 2) & 31;
            async_copy16(gchunk + (wcr * 32 + ii * 4 + (s & 3)),
                         (char*)&wbuf[buf][0] + (t * 256 + (tid & 192)) * 16);
        }
    };

    float4 acc[NCH][2];

    xld(0, 0);
    xld(1, 1);
    stage(0, 0);
    #pragma unroll
    for (int k = 0; k < NCH; ++k) {
        __syncthreads();               // stage(k) drained on all waves; other buf free
        if (k + 1 < NCH) stage(k + 1, (k + 1) & 1);
        // og-quad exchange: fA = sub sA floats 0..7, fB = sub sA+1 (VALU)
        const float4 cur = xvb[k & 1];
        float fA[8], fB[8];
        fA[0] = dpp_bc<0x00>(cur.x); fA[1] = dpp_bc<0x00>(cur.y);
        fA[2] = dpp_bc<0x00>(cur.z); fA[3] = dpp_bc<0x00>(cur.w);
        fA[4] = dpp_bc<0x55>(cur.x); fA[5] = dpp_bc<0x55>(cur.y);
        fA[6] = dpp_bc<0x55>(cur.z); fA[7] = dpp_bc<0x55>(cur.w);
        fB[0] = dpp_bc<0xAA>(cur.x); fB[1] = dpp_bc<0xAA>(cur.y);
        fB[2] = dpp_bc<0xAA>(cur.z); fB[3] = dpp_bc<0xAA>(cur.w);
        fB[4] = dpp_bc<0xFF>(cur.x); fB[5] = dpp_bc<0xFF>(cur.y);
        fB[6] = dpp_bc<0xFF>(cur.z); fB[7] = dpp_bc<0xFF>(cur.w);
        if (k + 2 < NCH) xld(k + 2, k & 1);   // slot freed (cur extracted)
        const float4* wb = &wbuf[k & 1][0];
        float4 a0 = make_float4(0.f, 0.f, 0.f, 0.f);
        float4 a1 = make_float4(0.f, 0.f, 0.f, 0.f);
        #pragma unroll
        for (int i = 0; i < 8; ++i) {
            const float4 wv4 = wb[i * 128 + cr * 4 + og];   // conflict-free b128
            a0.x = fmaf(fA[i], wv4.x, a0.x);  a1.x = fmaf(fB[i], wv4.x, a1.x);
            a0.y = fmaf(fA[i], wv4.y, a0.y);  a1.y = fmaf(fB[i], wv4.y, a1.y);
            a0.z = fmaf(fA[i], wv4.z, a0.z);  a1.z = fmaf(fB[i], wv4.z, a1.z);
            a0.w = fmaf(fA[i], wv4.w, a0.w);  a1.w = fmaf(fB[i], wv4.w, a1.w);
        }
        acc[k][0] = a0;  acc[k][1] = a1;
    }

    float lgA[NCH], lgB[NCH];
    #pragma unroll
    for (int j = 0; j < NCH; ++j) { lgA[j] = 0.f; lgB[j] = 0.f; }

    float4 v0, v1;   // squash output for subs sA, sA+1, couts og*4..og*4+3

    for (int it = 0; it < NITER; ++it) {
        const int par = it & 1;
        float4 s0 = make_float4(0.f, 0.f, 0.f, 0.f);
        float4 s1 = make_float4(0.f, 0.f, 0.f, 0.f);
        float se0 = 0.f, se1 = 0.f;

        if (it == 0) {
            #pragma unroll
            for (int j = 0; j < NCH; ++j) {
                s0.x += acc[j][0].x;  s1.x += acc[j][1].x;
                s0.y += acc[j][0].y;  s1.y += acc[j][1].y;
                s0.z += acc[j][0].z;  s1.z += acc[j][1].z;
                s0.w += acc[j][0].w;  s1.w += acc[j][1].w;
            }
        } else {
            #pragma unroll
            for (int j = 0; j < NCH; ++j) {
                float d0 = dot4(acc[j][0], v0);
                float d1 = dot4(acc[j][1], v1);
                d0 = dpp_add_xor1(d0);  d1 = dpp_add_xor1(d1);   // VALU
                d0 = dpp_add_xor2(d0);  d1 = dpp_add_xor2(d1);
                lgA[j] += d0;                 lgB[j] += d1;
                const float e0 = __expf(lgA[j]);
                const float e1 = __expf(lgB[j]);
                se0 += e0;                    se1 += e1;
                s0.x = fmaf(e0, acc[j][0].x, s0.x);  s1.x = fmaf(e1, acc[j][1].x, s1.x);
                s0.y = fmaf(e0, acc[j][0].y, s0.y);  s1.y = fmaf(e1, acc[j][1].y, s1.y);
                s0.z = fmaf(e0, acc[j][0].z, s0.z);  s1.z = fmaf(e1, acc[j][1].z, s1.z);
                s0.w = fmaf(e0, acc[j][0].w, s0.w);  s1.w = fmaf(e1, acc[j][1].w, s1.w);
            }
            // se: og-redundant; lane bits 2-3 on DPP, 4-5 on swizzle
            se0 = dpp_add_shr4(se0);  se1 = dpp_add_shr4(se1);
            se0 = dpp_add_shr8(se0);  se1 = dpp_add_shr8(se1);
            se0 += __shfl_xor(se0, 16, 64);  se1 += __shfl_xor(se1, 16, 64);
            se0 += __shfl_xor(se0, 32, 64);  se1 += __shfl_xor(se1, 32, 64);
            if (lane == 15) { redE[par][wv][0] = se0; redE[par][wv][1] = se1; }
        }

        // s-reduce over the wave's 16 cr-slots: bits 2-3 via DPP row_shr
        // (og-preserving; totals in lanes 12..15), bits 4-5 via swizzle.
        s0.x = dpp_add_shr4(s0.x);  s1.x = dpp_add_shr4(s1.x);
        s0.y = dpp_add_shr4(s0.y);  s1.y = dpp_add_shr4(s1.y);
        s0.z = dpp_add_shr4(s0.z);  s1.z = dpp_add_shr4(s1.z);
        s0.w = dpp_add_shr4(s0.w);  s1.w = dpp_add_shr4(s1.w);
        s0.x = dpp_add_shr8(s0.x);  s1.x = dpp_add_shr8(s1.x);
        s0.y = dpp_add_shr8(s0.y);  s1.y = dpp_add_shr8(s1.y);
        s0.z = dpp_add_shr8(s0.z);  s1.z = dpp_add_shr8(s1.z);
        s0.w = dpp_add_shr8(s0.w);  s1.w = dpp_add_shr8(s1.w);
        #pragma unroll
        for (int off = 16; off <= 32; off <<= 1) {
            s0.x += __shfl_xor(s0.x, off, 64);  s1.x += __shfl_xor(s1.x, off, 64);
            s0.y += __shfl_xor(s0.y, off, 64);  s1.y += __shfl_xor(s1.y, off, 64);
            s0.z += __shfl_xor(s0.z, off, 64);  s1.z += __shfl_xor(s1.z, off, 64);
            s0.w += __shfl_xor(s0.w, off, 64);  s1.w += __shfl_xor(s1.w, off, 64);
        }
        if (lane >= 12 && lane < 16) {   // lanes 12..15, og = lane&3
            *(float4*)&sRed[par][wv][0][(lane & 3) * 4] = s0;
            *(float4*)&sRed[par][wv][1][(lane & 3) * 4] = s1;
        }
        __syncthreads();

        // ---- all-wave redundant squash (R15): every thread computes its
        // own og-quad of v for subs sA, sA+1 (no divergent phase, no vS).
        const float4 pa0 = *(const float4*)&sRed[par][sh * 2    ][0][og * 4];
        const float4 pb0 = *(const float4*)&sRed[par][sh * 2 + 1][0][og * 4];
        const float4 pa1 = *(const float4*)&sRed[par][sh * 2    ][1][og * 4];
        const float4 pb1 = *(const float4*)&sRed[par][sh * 2 + 1][1][og * 4];
        float inv0, inv1;
        if (it == 0) {
            inv0 = inv1 = 1.0f / (float)R_;
        } else {
            inv0 = 1.0f / (redE[par][sh * 2][0] + redE[par][sh * 2 + 1][0]);
            inv1 = 1.0f / (redE[par][sh * 2][1] + redE[par][sh * 2 + 1][1]);
        }
        float4 sc0, sc1;
        sc0.x = (pa0.x + pb0.x) * inv0;  sc1.x = (pa1.x + pb1.x) * inv1;
        sc0.y = (pa0.y + pb0.y) * inv0;  sc1.y = (pa1.y + pb1.y) * inv1;
        sc0.z = (pa0.z + pb0.z) * inv0;  sc1.z = (pa1.z + pb1.z) * inv1;
        sc0.w = (pa0.w + pb0.w) * inv0;  sc1.w = (pa1.w + pb1.w) * inv1;
        float sn0 = dot4(sc0, sc0);
        float sn1 = dot4(sc1, sc1);
        sn0 = dpp_add_xor1(sn0);  sn1 = dpp_add_xor1(sn1);   // sum over og quad
        sn0 = dpp_add_xor2(sn0);  sn1 = dpp_add_xor2(sn1);
        const float f0 = sqrtf(sn0) / (1.0f + sn0);
        const float f1 = sqrtf(sn1) / (1.0f + sn1);
        v0.x = sc0.x * f0;  v1.x = sc1.x * f1;
        v0.y = sc0.y * f0;  v1.y = sc1.y * f1;
        v0.z = sc0.z * f0;  v1.z = sc1.z * f1;
        v0.w = sc0.w * f0;  v1.w = sc1.w * f1;
        // Next iter writes sRed/redE[!par]; the par-buffer overwrite (it+2)
        // sits behind it+1's barrier.
    }

    if (cr == 0) {   // 8 writer threads: (sh 0..1) x (og 0..3), 2 subs each
        *(float4*)&out[((((size_t)(b0 + sA)     * C_ + c) * W_ + p) * W_ + q) * COUT + og * 4] = v0;
        *(float4*)&out[((((size_t)(b0 + sA + 1) * C_ + c) * W_ + p) * W_ + q) * COUT + og * 4] = v1;
    }
}

extern "C" void kernel_launch(void* const* d_in, const int* in_sizes, int n_in,
                              void* d_out, int out_size, void* d_ws, size_t ws_size,
                              hipStream_t stream) {
    const float* x  = (const float*)d_in[0];
    const float* rw = (const float*)d_in[1];
    float* out = (float*)d_out;
    caps_routeC<<<dim3(W_ * W_ * 2 * C_), 256, 0, stream>>>(x, rw, out);
}